// Round 8
// baseline (3019.918 us; speedup 1.0000x reference)
//
#include <hip/hip_runtime.h>
#include <cstdint>

static constexpr int B   = 8;
static constexpr int N0  = 4096;
static constexpr int NQ  = 1024;
static constexpr int KNB = 16;

// ---------------------------------------------------------------------------
// DPP helpers. ctrl must be a compile-time constant -> template parameter.
// row_shr 1,2,4,8 + row_bcast15/31; full-wave result in lane 63.
// update_dpp(old=x, src=x): invalid lanes keep x (identity).
// ---------------------------------------------------------------------------
template <int CTRL>
__device__ __forceinline__ int dpp_i32(int x) {
  return __builtin_amdgcn_update_dpp(x, x, CTRL, 0xf, 0xf, false);
}

__device__ __forceinline__ float wave_min_bcast_f32(float x) {
#define STEP_(ctrl)                                                                     \
  {                                                                                     \
    int t_ = dpp_i32<ctrl>(__float_as_int(x));                                          \
    x = fminf(x, __int_as_float(t_));                                                   \
  }
  STEP_(0x111) STEP_(0x112) STEP_(0x114) STEP_(0x118) STEP_(0x142) STEP_(0x143)
#undef STEP_
  return __int_as_float(__builtin_amdgcn_readlane(__float_as_int(x), 63));
}

__device__ __forceinline__ unsigned wave_min_bcast_u32(unsigned x) {
#define STEP_(ctrl)                                                                     \
  {                                                                                     \
    unsigned t_ = (unsigned)dpp_i32<ctrl>((int)x);                                      \
    x = (t_ < x) ? t_ : x;                                                              \
  }
  STEP_(0x111) STEP_(0x112) STEP_(0x114) STEP_(0x118) STEP_(0x142) STEP_(0x143)
#undef STEP_
  return (unsigned)__builtin_amdgcn_readlane((int)x, 63);
}

// ---------------------------------------------------------------------------
// prep: split x; write packed c4 = {x,y,z,|c|^2}, normal, plane, f0
// ---------------------------------------------------------------------------
__global__ void prep_kernel(const float* __restrict__ x,
                            const float* __restrict__ W_in,
                            const float* __restrict__ b_in,
                            float4* __restrict__ c4, float* __restrict__ nrm,
                            float* __restrict__ pl, float* __restrict__ f0) {
  int i = blockIdx.x * 256 + threadIdx.x;
  if (i >= B * N0) return;
  const float* xp = x + (size_t)i * 7;
  float cx = xp[0], cy = xp[1], cz = xp[2];
  // tie-sensitive (feeds kNN distance): exact fp32, ref association order
  float kk = __fadd_rn(__fadd_rn(__fmul_rn(cx, cx), __fmul_rn(cy, cy)), __fmul_rn(cz, cz));
  c4[i] = make_float4(cx, cy, cz, kk);
  nrm[i * 3 + 0] = xp[3]; nrm[i * 3 + 1] = xp[4]; nrm[i * 3 + 2] = xp[5];
  pl[i] = xp[6];
#pragma unroll
  for (int o = 0; o < 8; o++) {
    f0[(size_t)i * 8 + o] = cx * W_in[o * 3 + 0] + cy * W_in[o * 3 + 1] + cz * W_in[o * 3 + 2] + b_in[o];
  }
}

// ---------------------------------------------------------------------------
// kNN body: wave per query (bq). Lane owns M=Nk/64 candidates.
// 16 rounds of DPP wave argmin (tie -> smaller index == stable top_k).
// d2 = ((|q|^2 - 2*dot) + |k|^2), exact fp32 non-fused like the reference.
// ---------------------------------------------------------------------------
template <int M>
__device__ __forceinline__ void knn_body(int bq, int lane,
                                         const float4* __restrict__ q4,
                                         const float4* __restrict__ k4,
                                         int Q, int Nk, int* __restrict__ out) {
  int b = bq / Q;
  float4 q = q4[bq];
  const float4* kb = k4 + (size_t)b * Nk;
  float d[M];
#pragma unroll
  for (int i = 0; i < M; i++) {
    float4 kp = kb[i * 64 + lane];
    float dot = __fadd_rn(__fadd_rn(__fmul_rn(q.x, kp.x), __fmul_rn(q.y, kp.y)),
                          __fmul_rn(q.z, kp.z));
    d[i] = __fadd_rn(__fsub_rn(q.w, __fmul_rn(2.0f, dot)), kp.w);
  }
  unsigned long long mask = 0ull;
  float lv = 3.0e38f; int li = 0;
#pragma unroll
  for (int i = 0; i < M; i++) { if (d[i] < lv) { lv = d[i]; li = i; } }
  int mynb = 0;
  for (int r = 0; r < KNB; r++) {
    int n = li * 64 + lane;
    float wmin = wave_min_bcast_f32(lv);
    unsigned ci = (lv == wmin) ? (unsigned)n : 0xFFFFFFFFu;
    int wn = (int)wave_min_bcast_u32(ci);
    if (lane == r) mynb = wn;
    if (lane == (wn & 63)) {  // owner lane: mark + rescan
      mask |= 1ull << (wn >> 6);
      lv = 3.0e38f; li = 0;
#pragma unroll
      for (int i = 0; i < M; i++) {
        bool dead = (mask >> i) & 1ull;
        float dv = dead ? 3.0e38f : d[i];
        if (dv < lv) { lv = dv; li = i; }
      }
    }
  }
  if (lane < KNB) out[(size_t)bq * KNB + lane] = mynb;
}

// ---------------------------------------------------------------------------
// ctrY body: ctrY[b,q,o] = sum_c fq_row[c] * W[o, CF+c]; optional row
// indirection (fq_row = fq[b*Nsrc + ridx[bq]]) replaces the f-gather.
// ---------------------------------------------------------------------------
template <int CF, int CO>
__device__ __forceinline__ void ctry_body(int i, int total, const float* __restrict__ fq,
                                          const float* __restrict__ W,
                                          float* __restrict__ ctrY,
                                          const int* __restrict__ ridx, int Q, int Nsrc) {
  if (i >= total) return;
  int o = i % CO, bq = i / CO;
  const float* fp;
  if (ridx) {
    int b = bq / Q;
    fp = fq + ((size_t)b * Nsrc + ridx[bq]) * CF;
  } else {
    fp = fq + (size_t)bq * CF;
  }
  const float* wp = W + (size_t)o * (2 * CF) + CF;
  float acc = 0.f;
#pragma unroll
  for (int c = 0; c < CF; c++) acc = fmaf(fp[c], wp[c], acc);
  ctrY[i] = acc;
}

// ---------------------------------------------------------------------------
// FPS v6: BLK=256 (4 waves/block), one block per batch, selects NQ points.
// Phase A: candidate pairs as float2 + fp contract(off) -> v_pk_{sub,mul,add}
// (identical rn rounding; no fma). Tail: the DPP argmax chain carries
// (key, x, y, z) together (3 extra cndmask/step) so lane 63 ends with the
// winner's key AND coords -> slot write; after ONE barrier all lanes read
// 2x ulonglong2 keys + 4x float4 coords INDEPENDENTLY and run a 3-level
// cndmask select tree (winner key unique: embeds distinct index). No scalar
// ops, no dependent 2nd LDS read, ~400 B LDS total (was 48 KB -> unfreezes
// cohabitant knn occupancy). Key=(dist_bits<<12)|(4095-bi): u64 max ==
// (max dist, tie min index) == jnp.argmax (dists >= 0).
// ---------------------------------------------------------------------------
template <int NPTS>
__device__ __forceinline__ void fps_body(const float4* __restrict__ cb, int* w) {
#pragma clang fp contract(off)
  constexpr int BLK = 256;
  constexpr int M = NPTS / BLK;   // 16 or 4
  constexpr int MH = M / 2;
  constexpr int NW = BLK / 64;    // 4
  __shared__ __align__(16) unsigned long long skey[2][NW];
  __shared__ __align__(16) float4 scrd[2][NW];
  const int tid = threadIdx.x;
  const int wid = tid >> 6, lane = tid & 63;
  float2 xx[MH], yy[MH], zz[MH], dd[MH];
#pragma unroll
  for (int j = 0; j < MH; j++) {
    float4 p0 = cb[tid * M + 2 * j];
    float4 p1 = cb[tid * M + 2 * j + 1];
    xx[j] = make_float2(p0.x, p1.x);
    yy[j] = make_float2(p0.y, p1.y);
    zz[j] = make_float2(p0.z, p1.z);
    dd[j] = make_float2(3.4e38f, 3.4e38f);
  }
  w[0] = w[1] = w[2] = w[3] = 0;
  float4 pp = cb[0];
  float px = pp.x, py = pp.y, pz = pp.z;
  const int base = tid * M;
  for (int t = 1; t < NQ; t++) {
    float2 px2 = make_float2(px, px);
    float2 py2 = make_float2(py, py);
    float2 pz2 = make_float2(pz, pz);
    float bv = -1.f; int bj = 0; int odd = 0;
#pragma unroll
    for (int j = 0; j < MH; j++) {
      float2 dx = xx[j] - px2;
      float2 dy = yy[j] - py2;
      float2 dz = zz[j] - pz2;
      float2 d = dx * dx + dy * dy;     // ((dx^2+dy^2)+dz^2), rn, no contract
      d = d + dz * dz;
      float t0 = fminf(dd[j].x, d.x); dd[j].x = t0;
      float t1 = fminf(dd[j].y, d.y); dd[j].y = t1;
      if (t0 > bv) { bv = t0; bj = j; odd = 0; }   // strict >: first index wins
      if (t1 > bv) { bv = t1; bj = j; odd = 1; }
    }
    int bi = base + 2 * bj + odd;
    float bx = odd ? xx[bj].y : xx[bj].x;
    float by = odd ? yy[bj].y : yy[bj].x;
    float bz = odd ? zz[bj].y : zz[bj].x;
    // intra-wave argmax carrying coords: 6 DPP steps on (key, x, y, z)
    unsigned klo = (unsigned)(((unsigned)__float_as_uint(bv) << 12) | (unsigned)(4095 - bi));
    unsigned khi = (unsigned)(__float_as_uint(bv) >> 20);
#define STEPC_(ctrl)                                                                    \
    {                                                                                   \
      unsigned plo = (unsigned)dpp_i32<ctrl>((int)klo);                                 \
      unsigned phi = (unsigned)dpp_i32<ctrl>((int)khi);                                 \
      float qx = __int_as_float(dpp_i32<ctrl>(__float_as_int(bx)));                     \
      float qy = __int_as_float(dpp_i32<ctrl>(__float_as_int(by)));                     \
      float qz = __int_as_float(dpp_i32<ctrl>(__float_as_int(bz)));                     \
      bool gt = (phi > khi) || (phi == khi && plo > klo);                               \
      if (gt) { klo = plo; khi = phi; bx = qx; by = qy; bz = qz; }                      \
    }
    STEPC_(0x111) STEPC_(0x112) STEPC_(0x114) STEPC_(0x118) STEPC_(0x142) STEPC_(0x143)
#undef STEPC_
    int p = t & 1;
    if (lane == 63) {
      skey[p][wid] = ((unsigned long long)khi << 32) | klo;
      scrd[p][wid] = make_float4(bx, by, bz, 0.f);
    }
    __syncthreads();
    ulonglong2 kab = *(const ulonglong2*)&skey[p][0];
    ulonglong2 kcd = *(const ulonglong2*)&skey[p][2];
    float4 c0 = scrd[p][0], c1 = scrd[p][1], c2 = scrd[p][2], c3 = scrd[p][3];
    // 3-level select tree (keys unique)
    bool s01 = kab.y > kab.x;
    unsigned long long k01 = s01 ? kab.y : kab.x;
    float x01 = s01 ? c1.x : c0.x, y01 = s01 ? c1.y : c0.y, z01 = s01 ? c1.z : c0.z;
    bool s23 = kcd.y > kcd.x;
    unsigned long long k23 = s23 ? kcd.y : kcd.x;
    float x23 = s23 ? c3.x : c2.x, y23 = s23 ? c3.y : c2.y, z23 = s23 ? c3.z : c2.z;
    bool sf = k23 > k01;
    unsigned long long kf = sf ? k23 : k01;
    px = sf ? x23 : x01; py = sf ? y23 : y01; pz = sf ? z23 : z01;
    int win = 4095 - (int)(kf & 0xFFFull);
    if (t == tid) w[0] = win;
    if (t == tid + 256) w[1] = win;
    if (t == tid + 512) w[2] = win;
    if (t == tid + 768) w[3] = win;
  }
}

// ---------------------------------------------------------------------------
// mega1: blocks [0,8) fps1 (+ coord/nrm/pl gather tail); [8,8200) knn1;
// rest ctry1. All roles depend only on prep outputs; no inter-block deps.
// ---------------------------------------------------------------------------
__global__ __launch_bounds__(256, 2) void mega1_kernel(
    const float4* __restrict__ c40, const float* __restrict__ nrm,
    const float* __restrict__ pl, const float* __restrict__ f0,
    const float* __restrict__ W1, int* __restrict__ idx1,
    float4* __restrict__ c4q1, float* __restrict__ nq1, float* __restrict__ pq1,
    int* __restrict__ knn1, float* __restrict__ ctrY1) {
  int blk = blockIdx.x;
  if (blk < 8) {
    const int b = blk, tid = threadIdx.x;
    const float4* cb = c40 + (size_t)b * N0;
    int w[4];
    fps_body<N0>(cb, w);
    int* idxb = idx1 + (size_t)b * NQ;
#pragma unroll
    for (int u = 0; u < 4; u++) {
      int r = tid + u * 256;
      int s = (u == 0 && tid == 0) ? 0 : w[u];
      idxb[r] = s;
      c4q1[(size_t)b * NQ + r] = cb[s];
      const float* np = nrm + ((size_t)b * N0 + s) * 3;
      float* ndp = nq1 + ((size_t)b * NQ + r) * 3;
      ndp[0] = np[0]; ndp[1] = np[1]; ndp[2] = np[2];
      pq1[(size_t)b * NQ + r] = pl[(size_t)b * N0 + s];
    }
  } else if (blk < 8 + 8192) {
    int bq = (blk - 8) * 4 + (threadIdx.x >> 6);
    knn_body<64>(bq, threadIdx.x & 63, c40, c40, N0, N0, knn1);
  } else {
    int i = (blk - (8 + 8192)) * 256 + threadIdx.x;
    ctry_body<8, 32>(i, B * N0 * 32, f0, W1, ctrY1, nullptr, 0, 0);
  }
}

// ---------------------------------------------------------------------------
// mega2: blocks [0,8) fps2 (+ gather tail -> c4q2, d_out coords/normal/plane);
// [8,2056) knn2 (c4q1 vs c40); [2056,4104) knn3 (c4q1 vs c4q1); rest ctry2.
// All roles depend only on {mega1, gn_out1} outputs.
// ---------------------------------------------------------------------------
__global__ __launch_bounds__(256, 2) void mega2_kernel(
    const float4* __restrict__ c40, const float4* __restrict__ c4q1,
    const float* __restrict__ nq1, const float* __restrict__ pq1,
    const float* __restrict__ f1, const int* __restrict__ idx1,
    const float* __restrict__ W2, int* __restrict__ idx2,
    float4* __restrict__ c4q2, float* __restrict__ cq2out,
    float* __restrict__ nq2out, float* __restrict__ pq2out,
    int* __restrict__ knn2, int* __restrict__ knn3, float* __restrict__ ctrY2) {
  int blk = blockIdx.x;
  if (blk < 8) {
    const int b = blk, tid = threadIdx.x;
    const float4* cqb = c4q1 + (size_t)b * NQ;
    int w[4];
    fps_body<NQ>(cqb, w);
    int* idxb = idx2 + (size_t)b * NQ;
#pragma unroll
    for (int u = 0; u < 4; u++) {
      int r = tid + u * 256;
      int s = (u == 0 && tid == 0) ? 0 : w[u];
      idxb[r] = s;
      float4 c = cqb[s];
      c4q2[(size_t)b * NQ + r] = c;
      float* cd = cq2out + ((size_t)b * NQ + r) * 3;
      cd[0] = c.x; cd[1] = c.y; cd[2] = c.z;
      const float* np = nq1 + ((size_t)b * NQ + s) * 3;
      float* ndp = nq2out + ((size_t)b * NQ + r) * 3;
      ndp[0] = np[0]; ndp[1] = np[1]; ndp[2] = np[2];
      pq2out[(size_t)b * NQ + r] = pq1[(size_t)b * NQ + s];
    }
  } else if (blk < 8 + 2048) {
    int bq = (blk - 8) * 4 + (threadIdx.x >> 6);
    knn_body<64>(bq, threadIdx.x & 63, c4q1, c40, NQ, N0, knn2);
  } else if (blk < 8 + 4096) {
    int bq = (blk - (8 + 2048)) * 4 + (threadIdx.x >> 6);
    knn_body<16>(bq, threadIdx.x & 63, c4q1, c4q1, NQ, NQ, knn3);
  } else {
    int i = (blk - (8 + 4096)) * 256 + threadIdx.x;
    ctry_body<32, 64>(i, B * NQ * 64, f1, W2, ctrY2, idx1, NQ, N0);
  }
}

// ---------------------------------------------------------------------------
// mega3: blocks [0,2048) knn4 (c4q2 vs c4q1); rest ctry4 (f3 rows via idx2).
// ---------------------------------------------------------------------------
__global__ __launch_bounds__(256, 4) void mega3_kernel(
    const float4* __restrict__ c4q1, const float4* __restrict__ c4q2,
    const float* __restrict__ f3, const int* __restrict__ idx2,
    const float* __restrict__ W4, int* __restrict__ knn4, float* __restrict__ ctrY4) {
  int blk = blockIdx.x;
  if (blk < 2048) {
    int bq = blk * 4 + (threadIdx.x >> 6);
    knn_body<16>(bq, threadIdx.x & 63, c4q2, c4q1, NQ, NQ, knn4);
  } else {
    int i = (blk - 2048) * 256 + threadIdx.x;
    ctry_body<64, 128>(i, B * NQ * 128, f3, W4, ctrY4, idx2, NQ, NQ);
  }
}

// ---------------------------------------------------------------------------
// standalone ctry (layer 3, dense)
// ---------------------------------------------------------------------------
template <int CF, int CO>
__global__ void ctry_kernel(const float* __restrict__ fq, const float* __restrict__ W,
                            float* __restrict__ ctrY, int total) {
  int i = blockIdx.x * 256 + threadIdx.x;
  ctry_body<CF, CO>(i, total, fq, W, ctrY, nullptr, 0, 0);
}

// ---------------------------------------------------------------------------
// edge-conv pass A: wave per (b,q); lane = g*16+k. y = Wl*(nb-ctr) + ctrY;
// min/max over k per channel; per-(b,group) sum/sumsq. Optional ridx:
// center row = fq[b*Nk + ridx[bq]] (replaces f-gather).
// ---------------------------------------------------------------------------
template <int CF, int CO>
__global__ __launch_bounds__(256) void edgeconv_kernel(
    const float* __restrict__ fq, const float* __restrict__ fk,
    const int* __restrict__ knn, const float* __restrict__ Wfull,
    const float* __restrict__ ctrY, const int* __restrict__ ridx,
    float* __restrict__ ymin, float* __restrict__ ymax,
    float* __restrict__ gstats, int Q, int Nk) {
  constexpr int J = CO / 4;
  constexpr int SEC = J * CF + 8;
  __shared__ float Wl[4 * SEC];
  __shared__ float sstat[8];
  for (int t = threadIdx.x; t < CO * CF; t += 256) {
    int o = t / CF, c = t % CF;
    Wl[(o / J) * SEC + (o % J) * CF + c] = Wfull[(size_t)o * (2 * CF) + c];
  }
  if (threadIdx.x < 8) sstat[threadIdx.x] = 0.0f;
  __syncthreads();
  const int wid = threadIdx.x >> 6, lane = threadIdx.x & 63;
  const int bq = blockIdx.x * 4 + wid;
  const int b = bq / Q;
  const int g = lane >> 4, k = lane & 15;
  const int ni = knn[(size_t)bq * KNB + k];
  const float* nbp = fk + (size_t)(b * Nk + ni) * CF;
  const float* cp = ridx ? fq + ((size_t)b * Nk + ridx[bq]) * CF
                         : fq + (size_t)bq * CF;
  float acc[J];
#pragma unroll
  for (int j = 0; j < J; j++) acc[j] = 0.0f;
  const float* wg = &Wl[g * SEC];
#pragma unroll
  for (int c = 0; c < CF; c += 4) {
    float4 nb4 = *(const float4*)(nbp + c);
    float4 c4  = *(const float4*)(cp + c);
    float e0 = nb4.x - c4.x, e1 = nb4.y - c4.y, e2 = nb4.z - c4.z, e3 = nb4.w - c4.w;
#pragma unroll
    for (int j = 0; j < J; j++) {
      float4 w4 = *(const float4*)(wg + j * CF + c);
      acc[j] = fmaf(e0, w4.x, acc[j]);
      acc[j] = fmaf(e1, w4.y, acc[j]);
      acc[j] = fmaf(e2, w4.z, acc[j]);
      acc[j] = fmaf(e3, w4.w, acc[j]);
    }
  }
  float s = 0.f, s2 = 0.f;
  const float* cyp = ctrY + (size_t)bq * CO + g * J;
#pragma unroll
  for (int j = 0; j < J; j++) {
    float y = acc[j] + cyp[j];
    acc[j] = y;            // acc becomes running max
    s += y; s2 = fmaf(y, y, s2);
  }
  float mn[J];
#pragma unroll
  for (int j = 0; j < J; j++) mn[j] = acc[j];
#pragma unroll
  for (int m = 1; m < 16; m <<= 1) {  // reduce over the 16 k-lanes
#pragma unroll
    for (int j = 0; j < J; j++) {
      float a = __shfl_xor(acc[j], m); if (a > acc[j]) acc[j] = a;
      float c2 = __shfl_xor(mn[j], m); if (c2 < mn[j]) mn[j] = c2;
    }
    s  += __shfl_xor(s, m);
    s2 += __shfl_xor(s2, m);
  }
  if (k == 0) {
    float* mnp = ymin + (size_t)bq * CO + g * J;
    float* mxp = ymax + (size_t)bq * CO + g * J;
#pragma unroll
    for (int j = 0; j < J; j++) { mnp[j] = mn[j]; mxp[j] = acc[j]; }
    atomicAdd(&sstat[g], s);
    atomicAdd(&sstat[4 + g], s2);
  }
  __syncthreads();
  if (threadIdx.x < 8) atomicAdd(&gstats[b * 8 + threadIdx.x], sstat[threadIdx.x]);
}

// ---------------------------------------------------------------------------
// pass B (gn_final fused): f = lrelu((sel - m)*gw*rs + gb),
// sel = max over K if scale>=0 else min (monotone-commute, exact).
// ---------------------------------------------------------------------------
template <int CO>
__global__ void gn_out_kernel(const float* __restrict__ ymin, const float* __restrict__ ymax,
                              const float* __restrict__ gstats, const float* __restrict__ gw,
                              const float* __restrict__ gb, float* __restrict__ fout,
                              int total, int Q, float inv_cnt) {
  int i = blockIdx.x * 256 + threadIdx.x;
  if (i >= total) return;
  constexpr int J = CO / 4;
  int o = i % CO; int bq = i / CO; int b = bq / Q;
  int g = o / J;
  float m  = gstats[b * 8 + g] * inv_cnt;
  float s2 = gstats[b * 8 + 4 + g] * inv_cnt;
  float rs = rsqrtf(s2 - m * m + 1e-5f);
  float sc = gw[o] * rs;
  float sel = (sc >= 0.f) ? ymax[i] : ymin[i];
  float v = (sel - m) * sc + gb[o];
  fout[i] = (v > 0.f) ? v : 0.2f * v;
}

// ---------------------------------------------------------------------------
extern "C" void kernel_launch(void* const* d_in, const int* in_sizes, int n_in,
                              void* d_out, int out_size, void* d_ws, size_t ws_size,
                              hipStream_t stream) {
  (void)in_sizes; (void)n_in; (void)out_size; (void)ws_size;
  const float* x    = (const float*)d_in[0];
  const float* W_in = (const float*)d_in[1];
  const float* b_in = (const float*)d_in[2];
  const float* W1   = (const float*)d_in[3];
  const float* g1w  = (const float*)d_in[4];
  const float* g1b  = (const float*)d_in[5];
  const float* W2   = (const float*)d_in[6];
  const float* g2w  = (const float*)d_in[7];
  const float* g2b  = (const float*)d_in[8];
  const float* W3   = (const float*)d_in[9];
  const float* g3w  = (const float*)d_in[10];
  const float* g3b  = (const float*)d_in[11];
  const float* W4   = (const float*)d_in[12];
  const float* g4w  = (const float*)d_in[13];
  const float* g4b  = (const float*)d_in[14];

  float* ws = (float*)d_ws;
  size_t o_c40  = 0;                                         // float4-aligned
  size_t o_nrm  = o_c40  + (size_t)B * N0 * 4;
  size_t o_pl   = o_nrm  + (size_t)B * N0 * 3;
  size_t o_f0   = o_pl   + (size_t)B * N0;
  size_t o_f1   = o_f0   + (size_t)B * N0 * 8;
  size_t o_ctrY = o_f1   + (size_t)B * N0 * 32;
  size_t o_ymin = o_ctrY + (size_t)B * N0 * 32;
  size_t o_ymax = o_ymin + (size_t)B * N0 * 32;
  size_t o_knnA = o_ymax + (size_t)B * N0 * 32;              // int region
  size_t o_knnB = o_knnA + (size_t)B * N0 * KNB;             // int region
  size_t o_gst  = o_knnB + (size_t)B * NQ * KNB;
  size_t o_idx1 = o_gst  + 4 * B * 8;                        // int region
  size_t o_idx2 = o_idx1 + (size_t)B * NQ;                   // int region
  size_t o_c4q1 = o_idx2 + (size_t)B * NQ;                   // float4-aligned
  size_t o_c4q2 = o_c4q1 + (size_t)B * NQ * 4;               // float4-aligned
  size_t o_nq1  = o_c4q2 + (size_t)B * NQ * 4;
  size_t o_pq1  = o_nq1  + (size_t)B * NQ * 3;
  size_t o_f2   = o_pq1  + (size_t)B * NQ;
  size_t o_f3   = o_f2   + (size_t)B * NQ * 64;

  float4* c40  = (float4*)(ws + o_c40);
  float*  nrm  = ws + o_nrm;   float* pl   = ws + o_pl;
  float*  f0   = ws + o_f0;    float* f1   = ws + o_f1;
  float*  ctrY = ws + o_ctrY;  float* ymin = ws + o_ymin;  float* ymax = ws + o_ymax;
  int*    knnA = (int*)(ws + o_knnA);
  int*    knnB = (int*)(ws + o_knnB);
  float*  gst  = ws + o_gst;
  int*    idx1 = (int*)(ws + o_idx1);
  int*    idx2 = (int*)(ws + o_idx2);
  float4* c4q1 = (float4*)(ws + o_c4q1);
  float4* c4q2 = (float4*)(ws + o_c4q2);
  float*  nq1  = ws + o_nq1;   float* pq1  = ws + o_pq1;
  float*  f2   = ws + o_f2;    float* f3   = ws + o_f3;

  float* out  = (float*)d_out;
  float* cq2  = out;                                   // (B,NQ,3)
  float* fout = out + (size_t)B * NQ * 3;              // (B,NQ,128)
  float* nq2  = fout + (size_t)B * NQ * 128;           // (B,NQ,3)
  float* pq2  = nq2 + (size_t)B * NQ * 3;              // (B,NQ,1)

  (void)hipMemsetAsync(gst, 0, 4 * B * 8 * sizeof(float), stream);

  // stage 0
  prep_kernel<<<(B * N0 + 255) / 256, 256, 0, stream>>>(x, W_in, b_in, c40, nrm, pl, f0);

  // mega1: fps1 || knn1 || ctry1   (deps: prep only)
  mega1_kernel<<<8 + 8192 + 4096, 256, 0, stream>>>(c40, nrm, pl, f0, W1,
                                                    idx1, c4q1, nq1, pq1, knnA, ctrY);
  // layer 1 finish
  edgeconv_kernel<8, 32><<<B * N0 / 4, 256, 0, stream>>>(f0, f0, knnA, W1, ctrY, nullptr,
                                                         ymin, ymax, gst + 0, N0, N0);
  gn_out_kernel<32><<<(B * N0 * 32 + 255) / 256, 256, 0, stream>>>(
      ymin, ymax, gst + 0, g1w, g1b, f1, B * N0 * 32, N0, 1.0f / (4096.0f * 16.0f * 8.0f));

  // mega2: fps2 || knn2 || knn3 || ctry2   (deps: mega1 + gn_out1)
  mega2_kernel<<<8 + 2048 + 2048 + 2048, 256, 0, stream>>>(
      c40, c4q1, nq1, pq1, f1, idx1, W2, idx2, c4q2, cq2, nq2, pq2, knnA, knnB, ctrY);
  // layer 2 finish
  edgeconv_kernel<32, 64><<<B * NQ / 4, 256, 0, stream>>>(f1, f1, knnA, W2, ctrY, idx1,
                                                          ymin, ymax, gst + B * 8, NQ, N0);
  gn_out_kernel<64><<<(B * NQ * 64 + 255) / 256, 256, 0, stream>>>(
      ymin, ymax, gst + B * 8, g2w, g2b, f2, B * NQ * 64, NQ, 1.0f / (1024.0f * 16.0f * 16.0f));

  // layer 3 (dense, queries == keys == selected points)
  ctry_kernel<64, 64><<<(B * NQ * 64 + 255) / 256, 256, 0, stream>>>(f2, W3, ctrY, B * NQ * 64);
  edgeconv_kernel<64, 64><<<B * NQ / 4, 256, 0, stream>>>(f2, f2, knnB, W3, ctrY, nullptr,
                                                          ymin, ymax, gst + 2 * B * 8, NQ, NQ);
  gn_out_kernel<64><<<(B * NQ * 64 + 255) / 256, 256, 0, stream>>>(
      ymin, ymax, gst + 2 * B * 8, g3w, g3b, f3, B * NQ * 64, NQ, 1.0f / (1024.0f * 16.0f * 16.0f));

  // mega3: knn4 || ctry4   (deps: mega2 + gn_out3)
  mega3_kernel<<<2048 + 4096, 256, 0, stream>>>(c4q1, c4q2, f3, idx2, W4, knnB, ctrY);
  // layer 4 finish
  edgeconv_kernel<64, 128><<<B * NQ / 4, 256, 0, stream>>>(f3, f3, knnB, W4, ctrY, idx2,
                                                           ymin, ymax, gst + 3 * B * 8, NQ, NQ);
  gn_out_kernel<128><<<(B * NQ * 128 + 255) / 256, 256, 0, stream>>>(
      ymin, ymax, gst + 3 * B * 8, g4w, g4b, fout, B * NQ * 128, NQ, 1.0f / (1024.0f * 16.0f * 32.0f));
}

// Round 9
// 2392.181 us; speedup vs baseline: 1.2624x; 1.2624x over previous
//
#include <hip/hip_runtime.h>
#include <cstdint>

static constexpr int B   = 8;
static constexpr int N0  = 4096;
static constexpr int NQ  = 1024;
static constexpr int KNB = 16;

// ---------------------------------------------------------------------------
// DPP helpers. ctrl must be a compile-time constant -> template parameter.
// row_shr 1,2,4,8 + row_bcast15/31; full-wave result in lane 63.
// update_dpp(old=x, src=x): invalid lanes keep x (identity).
// ---------------------------------------------------------------------------
template <int CTRL>
__device__ __forceinline__ int dpp_i32(int x) {
  return __builtin_amdgcn_update_dpp(x, x, CTRL, 0xf, 0xf, false);
}

__device__ __forceinline__ float wave_min_bcast_f32(float x) {
#define STEP_(ctrl)                                                                     \
  {                                                                                     \
    int t_ = dpp_i32<ctrl>(__float_as_int(x));                                          \
    x = fminf(x, __int_as_float(t_));                                                   \
  }
  STEP_(0x111) STEP_(0x112) STEP_(0x114) STEP_(0x118) STEP_(0x142) STEP_(0x143)
#undef STEP_
  return __int_as_float(__builtin_amdgcn_readlane(__float_as_int(x), 63));
}

__device__ __forceinline__ unsigned wave_min_bcast_u32(unsigned x) {
#define STEP_(ctrl)                                                                     \
  {                                                                                     \
    unsigned t_ = (unsigned)dpp_i32<ctrl>((int)x);                                      \
    x = (t_ < x) ? t_ : x;                                                              \
  }
  STEP_(0x111) STEP_(0x112) STEP_(0x114) STEP_(0x118) STEP_(0x142) STEP_(0x143)
#undef STEP_
  return (unsigned)__builtin_amdgcn_readlane((int)x, 63);
}

// ---------------------------------------------------------------------------
// prep: split x; write packed c4 = {x,y,z,|c|^2}, normal, plane, f0
// ---------------------------------------------------------------------------
__global__ void prep_kernel(const float* __restrict__ x,
                            const float* __restrict__ W_in,
                            const float* __restrict__ b_in,
                            float4* __restrict__ c4, float* __restrict__ nrm,
                            float* __restrict__ pl, float* __restrict__ f0) {
  int i = blockIdx.x * 256 + threadIdx.x;
  if (i >= B * N0) return;
  const float* xp = x + (size_t)i * 7;
  float cx = xp[0], cy = xp[1], cz = xp[2];
  // tie-sensitive (feeds kNN distance): exact fp32, ref association order
  float kk = __fadd_rn(__fadd_rn(__fmul_rn(cx, cx), __fmul_rn(cy, cy)), __fmul_rn(cz, cz));
  c4[i] = make_float4(cx, cy, cz, kk);
  nrm[i * 3 + 0] = xp[3]; nrm[i * 3 + 1] = xp[4]; nrm[i * 3 + 2] = xp[5];
  pl[i] = xp[6];
#pragma unroll
  for (int o = 0; o < 8; o++) {
    f0[(size_t)i * 8 + o] = cx * W_in[o * 3 + 0] + cy * W_in[o * 3 + 1] + cz * W_in[o * 3 + 2] + b_in[o];
  }
}

// ---------------------------------------------------------------------------
// kNN body: wave per query (bq). Lane owns M=Nk/64 candidates.
// 16 rounds of DPP wave argmin (tie -> smaller index == stable top_k).
// d2 = ((|q|^2 - 2*dot) + |k|^2), exact fp32 non-fused like the reference.
// ---------------------------------------------------------------------------
template <int M>
__device__ __forceinline__ void knn_body(int bq, int lane,
                                         const float4* __restrict__ q4,
                                         const float4* __restrict__ k4,
                                         int Q, int Nk, int* __restrict__ out) {
  int b = bq / Q;
  float4 q = q4[bq];
  const float4* kb = k4 + (size_t)b * Nk;
  float d[M];
#pragma unroll
  for (int i = 0; i < M; i++) {
    float4 kp = kb[i * 64 + lane];
    float dot = __fadd_rn(__fadd_rn(__fmul_rn(q.x, kp.x), __fmul_rn(q.y, kp.y)),
                          __fmul_rn(q.z, kp.z));
    d[i] = __fadd_rn(__fsub_rn(q.w, __fmul_rn(2.0f, dot)), kp.w);
  }
  unsigned long long mask = 0ull;
  float lv = 3.0e38f; int li = 0;
#pragma unroll
  for (int i = 0; i < M; i++) { if (d[i] < lv) { lv = d[i]; li = i; } }
  int mynb = 0;
  for (int r = 0; r < KNB; r++) {
    int n = li * 64 + lane;
    float wmin = wave_min_bcast_f32(lv);
    unsigned ci = (lv == wmin) ? (unsigned)n : 0xFFFFFFFFu;
    int wn = (int)wave_min_bcast_u32(ci);
    if (lane == r) mynb = wn;
    if (lane == (wn & 63)) {  // owner lane: mark + rescan
      mask |= 1ull << (wn >> 6);
      lv = 3.0e38f; li = 0;
#pragma unroll
      for (int i = 0; i < M; i++) {
        bool dead = (mask >> i) & 1ull;
        float dv = dead ? 3.0e38f : d[i];
        if (dv < lv) { lv = dv; li = i; }
      }
    }
  }
  if (lane < KNB) out[(size_t)bq * KNB + lane] = mynb;
}

// ---------------------------------------------------------------------------
// ctrY body: ctrY[b,q,o] = sum_c fq_row[c] * W[o, CF+c]; optional row
// indirection (fq_row = fq[b*Nsrc + ridx[bq]]) replaces the f-gather.
// ---------------------------------------------------------------------------
template <int CF, int CO>
__device__ __forceinline__ void ctry_body(int i, int total, const float* __restrict__ fq,
                                          const float* __restrict__ W,
                                          float* __restrict__ ctrY,
                                          const int* __restrict__ ridx, int Q, int Nsrc) {
  if (i >= total) return;
  int o = i % CO, bq = i / CO;
  const float* fp;
  if (ridx) {
    int b = bq / Q;
    fp = fq + ((size_t)b * Nsrc + ridx[bq]) * CF;
  } else {
    fp = fq + (size_t)bq * CF;
  }
  const float* wp = W + (size_t)o * (2 * CF) + CF;
  float acc = 0.f;
#pragma unroll
  for (int c = 0; c < CF; c++) acc = fmaf(fp[c], wp[c], acc);
  ctrY[i] = acc;
}

// ---------------------------------------------------------------------------
// FPS v7: BLK=256 (4 waves/block), one block per batch, selects NQ points.
// Phase A: candidate pairs as float2 + fp contract(off) -> v_pk_{sub,mul,add}
// (identical rn rounding; no fma). Coords carried inside the UNROLLED loop
// with COMPILE-TIME indices (R8's post-loop xx[bj] runtime index triggered
// promote-alloca -> 16 KB LDS + 1.7M bank conflicts). Tail: DPP argmax chain
// carries (key,x,y,z); lane 63 writes slot; after ONE barrier 6 independent
// LDS reads + 3-level cndmask select tree (keys unique). ~200 B LDS total.
// Key=(dist_bits<<12)|(4095-bi): u64 max == (max dist, tie min index) ==
// jnp.argmax first-occurrence (dists >= 0). Winners buffered in registers.
// ---------------------------------------------------------------------------
template <int NPTS>
__device__ __forceinline__ void fps_body(const float4* __restrict__ cb, int* w) {
#pragma clang fp contract(off)
  constexpr int BLK = 256;
  constexpr int M = NPTS / BLK;   // 16 or 4
  constexpr int MH = M / 2;
  constexpr int NW = BLK / 64;    // 4
  __shared__ __align__(16) unsigned long long skey[2][NW];
  __shared__ __align__(16) float4 scrd[2][NW];
  const int tid = threadIdx.x;
  const int wid = tid >> 6, lane = tid & 63;
  float2 xx[MH], yy[MH], zz[MH], dd[MH];
#pragma unroll
  for (int j = 0; j < MH; j++) {
    float4 p0 = cb[tid * M + 2 * j];
    float4 p1 = cb[tid * M + 2 * j + 1];
    xx[j] = make_float2(p0.x, p1.x);
    yy[j] = make_float2(p0.y, p1.y);
    zz[j] = make_float2(p0.z, p1.z);
    dd[j] = make_float2(3.4e38f, 3.4e38f);
  }
  w[0] = w[1] = w[2] = w[3] = 0;
  float4 pp = cb[0];
  float px = pp.x, py = pp.y, pz = pp.z;
  const int base = tid * M;
  for (int t = 1; t < NQ; t++) {
    float2 px2 = make_float2(px, px);
    float2 py2 = make_float2(py, py);
    float2 pz2 = make_float2(pz, pz);
    float bv = -1.f; int bi = 0;
    float bx = 0.f, by = 0.f, bz = 0.f;
#pragma unroll
    for (int j = 0; j < MH; j++) {
      float2 dx = xx[j] - px2;
      float2 dy = yy[j] - py2;
      float2 dz = zz[j] - pz2;
      float2 d = dx * dx + dy * dy;     // ((dx^2+dy^2)+dz^2), rn, no contract
      d = d + dz * dz;
      float t0 = fminf(dd[j].x, d.x); dd[j].x = t0;
      float t1 = fminf(dd[j].y, d.y); dd[j].y = t1;
      // compile-time component selects only (keeps arrays in VGPRs)
      if (t0 > bv) { bv = t0; bi = base + 2 * j;     bx = xx[j].x; by = yy[j].x; bz = zz[j].x; }
      if (t1 > bv) { bv = t1; bi = base + 2 * j + 1; bx = xx[j].y; by = yy[j].y; bz = zz[j].y; }
    }
    // intra-wave argmax carrying coords: 6 DPP steps on (key, x, y, z)
    unsigned klo = (unsigned)(((unsigned)__float_as_uint(bv) << 12) | (unsigned)(4095 - bi));
    unsigned khi = (unsigned)(__float_as_uint(bv) >> 20);
#define STEPC_(ctrl)                                                                    \
    {                                                                                   \
      unsigned plo = (unsigned)dpp_i32<ctrl>((int)klo);                                 \
      unsigned phi = (unsigned)dpp_i32<ctrl>((int)khi);                                 \
      float qx = __int_as_float(dpp_i32<ctrl>(__float_as_int(bx)));                     \
      float qy = __int_as_float(dpp_i32<ctrl>(__float_as_int(by)));                     \
      float qz = __int_as_float(dpp_i32<ctrl>(__float_as_int(bz)));                     \
      bool gt = (phi > khi) || (phi == khi && plo > klo);                               \
      if (gt) { klo = plo; khi = phi; bx = qx; by = qy; bz = qz; }                      \
    }
    STEPC_(0x111) STEPC_(0x112) STEPC_(0x114) STEPC_(0x118) STEPC_(0x142) STEPC_(0x143)
#undef STEPC_
    int p = t & 1;
    if (lane == 63) {
      skey[p][wid] = ((unsigned long long)khi << 32) | klo;
      scrd[p][wid] = make_float4(bx, by, bz, 0.f);
    }
    __syncthreads();
    ulonglong2 kab = *(const ulonglong2*)&skey[p][0];
    ulonglong2 kcd = *(const ulonglong2*)&skey[p][2];
    float4 c0 = scrd[p][0], c1 = scrd[p][1], c2 = scrd[p][2], c3 = scrd[p][3];
    // 3-level select tree (keys unique)
    bool s01 = kab.y > kab.x;
    unsigned long long k01 = s01 ? kab.y : kab.x;
    float x01 = s01 ? c1.x : c0.x, y01 = s01 ? c1.y : c0.y, z01 = s01 ? c1.z : c0.z;
    bool s23 = kcd.y > kcd.x;
    unsigned long long k23 = s23 ? kcd.y : kcd.x;
    float x23 = s23 ? c3.x : c2.x, y23 = s23 ? c3.y : c2.y, z23 = s23 ? c3.z : c2.z;
    bool sf = k23 > k01;
    unsigned long long kf = sf ? k23 : k01;
    px = sf ? x23 : x01; py = sf ? y23 : y01; pz = sf ? z23 : z01;
    int win = 4095 - (int)(kf & 0xFFFull);
    if (t == tid) w[0] = win;
    if (t == tid + 256) w[1] = win;
    if (t == tid + 512) w[2] = win;
    if (t == tid + 768) w[3] = win;
  }
}

// ---------------------------------------------------------------------------
// mega1: blocks [0,8) fps1 (+ coord/nrm/pl gather tail); [8,8200) knn1;
// rest ctry1. All roles depend only on prep outputs; no inter-block deps.
// ---------------------------------------------------------------------------
__global__ __launch_bounds__(256, 2) void mega1_kernel(
    const float4* __restrict__ c40, const float* __restrict__ nrm,
    const float* __restrict__ pl, const float* __restrict__ f0,
    const float* __restrict__ W1, int* __restrict__ idx1,
    float4* __restrict__ c4q1, float* __restrict__ nq1, float* __restrict__ pq1,
    int* __restrict__ knn1, float* __restrict__ ctrY1) {
  int blk = blockIdx.x;
  if (blk < 8) {
    const int b = blk, tid = threadIdx.x;
    const float4* cb = c40 + (size_t)b * N0;
    int w[4];
    fps_body<N0>(cb, w);
    int* idxb = idx1 + (size_t)b * NQ;
#pragma unroll
    for (int u = 0; u < 4; u++) {
      int r = tid + u * 256;
      int s = (u == 0 && tid == 0) ? 0 : w[u];
      idxb[r] = s;
      c4q1[(size_t)b * NQ + r] = cb[s];
      const float* np = nrm + ((size_t)b * N0 + s) * 3;
      float* ndp = nq1 + ((size_t)b * NQ + r) * 3;
      ndp[0] = np[0]; ndp[1] = np[1]; ndp[2] = np[2];
      pq1[(size_t)b * NQ + r] = pl[(size_t)b * N0 + s];
    }
  } else if (blk < 8 + 8192) {
    int bq = (blk - 8) * 4 + (threadIdx.x >> 6);
    knn_body<64>(bq, threadIdx.x & 63, c40, c40, N0, N0, knn1);
  } else {
    int i = (blk - (8 + 8192)) * 256 + threadIdx.x;
    ctry_body<8, 32>(i, B * N0 * 32, f0, W1, ctrY1, nullptr, 0, 0);
  }
}

// ---------------------------------------------------------------------------
// mega2: blocks [0,8) fps2 (+ gather tail -> c4q2, d_out coords/normal/plane);
// [8,2056) knn2 (c4q1 vs c40); [2056,4104) knn3 (c4q1 vs c4q1); rest ctry2.
// All roles depend only on {mega1, gn_out1} outputs.
// ---------------------------------------------------------------------------
__global__ __launch_bounds__(256, 2) void mega2_kernel(
    const float4* __restrict__ c40, const float4* __restrict__ c4q1,
    const float* __restrict__ nq1, const float* __restrict__ pq1,
    const float* __restrict__ f1, const int* __restrict__ idx1,
    const float* __restrict__ W2, int* __restrict__ idx2,
    float4* __restrict__ c4q2, float* __restrict__ cq2out,
    float* __restrict__ nq2out, float* __restrict__ pq2out,
    int* __restrict__ knn2, int* __restrict__ knn3, float* __restrict__ ctrY2) {
  int blk = blockIdx.x;
  if (blk < 8) {
    const int b = blk, tid = threadIdx.x;
    const float4* cqb = c4q1 + (size_t)b * NQ;
    int w[4];
    fps_body<NQ>(cqb, w);
    int* idxb = idx2 + (size_t)b * NQ;
#pragma unroll
    for (int u = 0; u < 4; u++) {
      int r = tid + u * 256;
      int s = (u == 0 && tid == 0) ? 0 : w[u];
      idxb[r] = s;
      float4 c = cqb[s];
      c4q2[(size_t)b * NQ + r] = c;
      float* cd = cq2out + ((size_t)b * NQ + r) * 3;
      cd[0] = c.x; cd[1] = c.y; cd[2] = c.z;
      const float* np = nq1 + ((size_t)b * NQ + s) * 3;
      float* ndp = nq2out + ((size_t)b * NQ + r) * 3;
      ndp[0] = np[0]; ndp[1] = np[1]; ndp[2] = np[2];
      pq2out[(size_t)b * NQ + r] = pq1[(size_t)b * NQ + s];
    }
  } else if (blk < 8 + 2048) {
    int bq = (blk - 8) * 4 + (threadIdx.x >> 6);
    knn_body<64>(bq, threadIdx.x & 63, c4q1, c40, NQ, N0, knn2);
  } else if (blk < 8 + 4096) {
    int bq = (blk - (8 + 2048)) * 4 + (threadIdx.x >> 6);
    knn_body<16>(bq, threadIdx.x & 63, c4q1, c4q1, NQ, NQ, knn3);
  } else {
    int i = (blk - (8 + 4096)) * 256 + threadIdx.x;
    ctry_body<32, 64>(i, B * NQ * 64, f1, W2, ctrY2, idx1, NQ, N0);
  }
}

// ---------------------------------------------------------------------------
// mega3: blocks [0,2048) knn4 (c4q2 vs c4q1); rest ctry4 (f3 rows via idx2).
// ---------------------------------------------------------------------------
__global__ __launch_bounds__(256, 4) void mega3_kernel(
    const float4* __restrict__ c4q1, const float4* __restrict__ c4q2,
    const float* __restrict__ f3, const int* __restrict__ idx2,
    const float* __restrict__ W4, int* __restrict__ knn4, float* __restrict__ ctrY4) {
  int blk = blockIdx.x;
  if (blk < 2048) {
    int bq = blk * 4 + (threadIdx.x >> 6);
    knn_body<16>(bq, threadIdx.x & 63, c4q2, c4q1, NQ, NQ, knn4);
  } else {
    int i = (blk - 2048) * 256 + threadIdx.x;
    ctry_body<64, 128>(i, B * NQ * 128, f3, W4, ctrY4, idx2, NQ, NQ);
  }
}

// ---------------------------------------------------------------------------
// standalone ctry (layer 3, dense)
// ---------------------------------------------------------------------------
template <int CF, int CO>
__global__ void ctry_kernel(const float* __restrict__ fq, const float* __restrict__ W,
                            float* __restrict__ ctrY, int total) {
  int i = blockIdx.x * 256 + threadIdx.x;
  ctry_body<CF, CO>(i, total, fq, W, ctrY, nullptr, 0, 0);
}

// ---------------------------------------------------------------------------
// edge-conv pass A: wave per (b,q); lane = g*16+k. y = Wl*(nb-ctr) + ctrY;
// min/max over k per channel; per-(b,group) sum/sumsq. Optional ridx:
// center row = fq[b*Nk + ridx[bq]] (replaces f-gather).
// ---------------------------------------------------------------------------
template <int CF, int CO>
__global__ __launch_bounds__(256) void edgeconv_kernel(
    const float* __restrict__ fq, const float* __restrict__ fk,
    const int* __restrict__ knn, const float* __restrict__ Wfull,
    const float* __restrict__ ctrY, const int* __restrict__ ridx,
    float* __restrict__ ymin, float* __restrict__ ymax,
    float* __restrict__ gstats, int Q, int Nk) {
  constexpr int J = CO / 4;
  constexpr int SEC = J * CF + 8;
  __shared__ float Wl[4 * SEC];
  __shared__ float sstat[8];
  for (int t = threadIdx.x; t < CO * CF; t += 256) {
    int o = t / CF, c = t % CF;
    Wl[(o / J) * SEC + (o % J) * CF + c] = Wfull[(size_t)o * (2 * CF) + c];
  }
  if (threadIdx.x < 8) sstat[threadIdx.x] = 0.0f;
  __syncthreads();
  const int wid = threadIdx.x >> 6, lane = threadIdx.x & 63;
  const int bq = blockIdx.x * 4 + wid;
  const int b = bq / Q;
  const int g = lane >> 4, k = lane & 15;
  const int ni = knn[(size_t)bq * KNB + k];
  const float* nbp = fk + (size_t)(b * Nk + ni) * CF;
  const float* cp = ridx ? fq + ((size_t)b * Nk + ridx[bq]) * CF
                         : fq + (size_t)bq * CF;
  float acc[J];
#pragma unroll
  for (int j = 0; j < J; j++) acc[j] = 0.0f;
  const float* wg = &Wl[g * SEC];
#pragma unroll
  for (int c = 0; c < CF; c += 4) {
    float4 nb4 = *(const float4*)(nbp + c);
    float4 c4  = *(const float4*)(cp + c);
    float e0 = nb4.x - c4.x, e1 = nb4.y - c4.y, e2 = nb4.z - c4.z, e3 = nb4.w - c4.w;
#pragma unroll
    for (int j = 0; j < J; j++) {
      float4 w4 = *(const float4*)(wg + j * CF + c);
      acc[j] = fmaf(e0, w4.x, acc[j]);
      acc[j] = fmaf(e1, w4.y, acc[j]);
      acc[j] = fmaf(e2, w4.z, acc[j]);
      acc[j] = fmaf(e3, w4.w, acc[j]);
    }
  }
  float s = 0.f, s2 = 0.f;
  const float* cyp = ctrY + (size_t)bq * CO + g * J;
#pragma unroll
  for (int j = 0; j < J; j++) {
    float y = acc[j] + cyp[j];
    acc[j] = y;            // acc becomes running max
    s += y; s2 = fmaf(y, y, s2);
  }
  float mn[J];
#pragma unroll
  for (int j = 0; j < J; j++) mn[j] = acc[j];
#pragma unroll
  for (int m = 1; m < 16; m <<= 1) {  // reduce over the 16 k-lanes
#pragma unroll
    for (int j = 0; j < J; j++) {
      float a = __shfl_xor(acc[j], m); if (a > acc[j]) acc[j] = a;
      float c2 = __shfl_xor(mn[j], m); if (c2 < mn[j]) mn[j] = c2;
    }
    s  += __shfl_xor(s, m);
    s2 += __shfl_xor(s2, m);
  }
  if (k == 0) {
    float* mnp = ymin + (size_t)bq * CO + g * J;
    float* mxp = ymax + (size_t)bq * CO + g * J;
#pragma unroll
    for (int j = 0; j < J; j++) { mnp[j] = mn[j]; mxp[j] = acc[j]; }
    atomicAdd(&sstat[g], s);
    atomicAdd(&sstat[4 + g], s2);
  }
  __syncthreads();
  if (threadIdx.x < 8) atomicAdd(&gstats[b * 8 + threadIdx.x], sstat[threadIdx.x]);
}

// ---------------------------------------------------------------------------
// pass B (gn_final fused): f = lrelu((sel - m)*gw*rs + gb),
// sel = max over K if scale>=0 else min (monotone-commute, exact).
// ---------------------------------------------------------------------------
template <int CO>
__global__ void gn_out_kernel(const float* __restrict__ ymin, const float* __restrict__ ymax,
                              const float* __restrict__ gstats, const float* __restrict__ gw,
                              const float* __restrict__ gb, float* __restrict__ fout,
                              int total, int Q, float inv_cnt) {
  int i = blockIdx.x * 256 + threadIdx.x;
  if (i >= total) return;
  constexpr int J = CO / 4;
  int o = i % CO; int bq = i / CO; int b = bq / Q;
  int g = o / J;
  float m  = gstats[b * 8 + g] * inv_cnt;
  float s2 = gstats[b * 8 + 4 + g] * inv_cnt;
  float rs = rsqrtf(s2 - m * m + 1e-5f);
  float sc = gw[o] * rs;
  float sel = (sc >= 0.f) ? ymax[i] : ymin[i];
  float v = (sel - m) * sc + gb[o];
  fout[i] = (v > 0.f) ? v : 0.2f * v;
}

// ---------------------------------------------------------------------------
extern "C" void kernel_launch(void* const* d_in, const int* in_sizes, int n_in,
                              void* d_out, int out_size, void* d_ws, size_t ws_size,
                              hipStream_t stream) {
  (void)in_sizes; (void)n_in; (void)out_size; (void)ws_size;
  const float* x    = (const float*)d_in[0];
  const float* W_in = (const float*)d_in[1];
  const float* b_in = (const float*)d_in[2];
  const float* W1   = (const float*)d_in[3];
  const float* g1w  = (const float*)d_in[4];
  const float* g1b  = (const float*)d_in[5];
  const float* W2   = (const float*)d_in[6];
  const float* g2w  = (const float*)d_in[7];
  const float* g2b  = (const float*)d_in[8];
  const float* W3   = (const float*)d_in[9];
  const float* g3w  = (const float*)d_in[10];
  const float* g3b  = (const float*)d_in[11];
  const float* W4   = (const float*)d_in[12];
  const float* g4w  = (const float*)d_in[13];
  const float* g4b  = (const float*)d_in[14];

  float* ws = (float*)d_ws;
  size_t o_c40  = 0;                                         // float4-aligned
  size_t o_nrm  = o_c40  + (size_t)B * N0 * 4;
  size_t o_pl   = o_nrm  + (size_t)B * N0 * 3;
  size_t o_f0   = o_pl   + (size_t)B * N0;
  size_t o_f1   = o_f0   + (size_t)B * N0 * 8;
  size_t o_ctrY = o_f1   + (size_t)B * N0 * 32;
  size_t o_ymin = o_ctrY + (size_t)B * N0 * 32;
  size_t o_ymax = o_ymin + (size_t)B * N0 * 32;
  size_t o_knnA = o_ymax + (size_t)B * N0 * 32;              // int region
  size_t o_knnB = o_knnA + (size_t)B * N0 * KNB;             // int region
  size_t o_gst  = o_knnB + (size_t)B * NQ * KNB;
  size_t o_idx1 = o_gst  + 4 * B * 8;                        // int region
  size_t o_idx2 = o_idx1 + (size_t)B * NQ;                   // int region
  size_t o_c4q1 = o_idx2 + (size_t)B * NQ;                   // float4-aligned
  size_t o_c4q2 = o_c4q1 + (size_t)B * NQ * 4;               // float4-aligned
  size_t o_nq1  = o_c4q2 + (size_t)B * NQ * 4;
  size_t o_pq1  = o_nq1  + (size_t)B * NQ * 3;
  size_t o_f2   = o_pq1  + (size_t)B * NQ;
  size_t o_f3   = o_f2   + (size_t)B * NQ * 64;

  float4* c40  = (float4*)(ws + o_c40);
  float*  nrm  = ws + o_nrm;   float* pl   = ws + o_pl;
  float*  f0   = ws + o_f0;    float* f1   = ws + o_f1;
  float*  ctrY = ws + o_ctrY;  float* ymin = ws + o_ymin;  float* ymax = ws + o_ymax;
  int*    knnA = (int*)(ws + o_knnA);
  int*    knnB = (int*)(ws + o_knnB);
  float*  gst  = ws + o_gst;
  int*    idx1 = (int*)(ws + o_idx1);
  int*    idx2 = (int*)(ws + o_idx2);
  float4* c4q1 = (float4*)(ws + o_c4q1);
  float4* c4q2 = (float4*)(ws + o_c4q2);
  float*  nq1  = ws + o_nq1;   float* pq1  = ws + o_pq1;
  float*  f2   = ws + o_f2;    float* f3   = ws + o_f3;

  float* out  = (float*)d_out;
  float* cq2  = out;                                   // (B,NQ,3)
  float* fout = out + (size_t)B * NQ * 3;              // (B,NQ,128)
  float* nq2  = fout + (size_t)B * NQ * 128;           // (B,NQ,3)
  float* pq2  = nq2 + (size_t)B * NQ * 3;              // (B,NQ,1)

  (void)hipMemsetAsync(gst, 0, 4 * B * 8 * sizeof(float), stream);

  // stage 0
  prep_kernel<<<(B * N0 + 255) / 256, 256, 0, stream>>>(x, W_in, b_in, c40, nrm, pl, f0);

  // mega1: fps1 || knn1 || ctry1   (deps: prep only)
  mega1_kernel<<<8 + 8192 + 4096, 256, 0, stream>>>(c40, nrm, pl, f0, W1,
                                                    idx1, c4q1, nq1, pq1, knnA, ctrY);
  // layer 1 finish
  edgeconv_kernel<8, 32><<<B * N0 / 4, 256, 0, stream>>>(f0, f0, knnA, W1, ctrY, nullptr,
                                                         ymin, ymax, gst + 0, N0, N0);
  gn_out_kernel<32><<<(B * N0 * 32 + 255) / 256, 256, 0, stream>>>(
      ymin, ymax, gst + 0, g1w, g1b, f1, B * N0 * 32, N0, 1.0f / (4096.0f * 16.0f * 8.0f));

  // mega2: fps2 || knn2 || knn3 || ctry2   (deps: mega1 + gn_out1)
  mega2_kernel<<<8 + 2048 + 2048 + 2048, 256, 0, stream>>>(
      c40, c4q1, nq1, pq1, f1, idx1, W2, idx2, c4q2, cq2, nq2, pq2, knnA, knnB, ctrY);
  // layer 2 finish
  edgeconv_kernel<32, 64><<<B * NQ / 4, 256, 0, stream>>>(f1, f1, knnA, W2, ctrY, idx1,
                                                          ymin, ymax, gst + B * 8, NQ, N0);
  gn_out_kernel<64><<<(B * NQ * 64 + 255) / 256, 256, 0, stream>>>(
      ymin, ymax, gst + B * 8, g2w, g2b, f2, B * NQ * 64, NQ, 1.0f / (1024.0f * 16.0f * 16.0f));

  // layer 3 (dense, queries == keys == selected points)
  ctry_kernel<64, 64><<<(B * NQ * 64 + 255) / 256, 256, 0, stream>>>(f2, W3, ctrY, B * NQ * 64);
  edgeconv_kernel<64, 64><<<B * NQ / 4, 256, 0, stream>>>(f2, f2, knnB, W3, ctrY, nullptr,
                                                          ymin, ymax, gst + 2 * B * 8, NQ, NQ);
  gn_out_kernel<64><<<(B * NQ * 64 + 255) / 256, 256, 0, stream>>>(
      ymin, ymax, gst + 2 * B * 8, g3w, g3b, f3, B * NQ * 64, NQ, 1.0f / (1024.0f * 16.0f * 16.0f));

  // mega3: knn4 || ctry4   (deps: mega2 + gn_out3)
  mega3_kernel<<<2048 + 4096, 256, 0, stream>>>(c4q1, c4q2, f3, idx2, W4, knnB, ctrY);
  // layer 4 finish
  edgeconv_kernel<64, 128><<<B * NQ / 4, 256, 0, stream>>>(f3, f3, knnB, W4, ctrY, idx2,
                                                           ymin, ymax, gst + 3 * B * 8, NQ, NQ);
  gn_out_kernel<128><<<(B * NQ * 128 + 255) / 256, 256, 0, stream>>>(
      ymin, ymax, gst + 3 * B * 8, g4w, g4b, fout, B * NQ * 128, NQ, 1.0f / (1024.0f * 16.0f * 32.0f));
}